// Round 17
// baseline (100.040 us; speedup 1.0000x reference)
//
#include <hip/hip_runtime.h>
#include <hip/hip_bf16.h>

#define NCOLS 32768
#define NZ 64
#define NT 40
#define DTF 30.0f
#define GAMMAC 0.55f

typedef _Float16 f16;
typedef __fp16 h2v __attribute__((ext_vector_type(2)));

#if __has_builtin(__builtin_amdgcn_fdot2) && __has_builtin(__builtin_amdgcn_cvt_pkrtz)
#define HAS_DOT2 1
#else
#define HAS_DOT2 0
#endif

// Cap the pre-RA scheduler's prefetch window (r4->r5 lesson).
#define SBAR() __builtin_amdgcn_sched_barrier(0)
#define RCP(x) __builtin_amdgcn_rcpf(x)

// swap lanes (0,1) and (2,3) within each quad: u<->v, t<->s
__device__ __forceinline__ float dpp_swap1(float x) {
    return __int_as_float(__builtin_amdgcn_mov_dpp(__float_as_int(x), 0xB1, 0xF, 0xF, true));
}
__device__ __forceinline__ unsigned int packh2(float a, float b) {
    union { f16 h[2]; unsigned int u; } v;
    v.h[0] = (f16)a; v.h[1] = (f16)b; return v.u;
}
__device__ __forceinline__ unsigned short f16bits(float a) {
    union { f16 h; unsigned short u; } v; v.h = (f16)a; return v.u;
}
__device__ __forceinline__ float lo16f(unsigned int x) {
    union { unsigned int u; f16 h[2]; } v; v.u = x; return (float)v.h[0];
}
__device__ __forceinline__ float hi16f(unsigned int x) {
    union { unsigned int u; f16 h[2]; } v; v.u = x; return (float)v.h[1];
}
__device__ __forceinline__ h2v u2h(unsigned int x) {
    union { unsigned int u; h2v h; } v; v.u = x; return v.h;
}

// r17 = r16 with the cvt_pkrtz type fixed (__fp16 vector, not _Float16).
// r16 theory (unfalsified): hot loop is VALU-issue-bound; v_dot2_f32_f16
// collapses {unpack-lo, fma, unpack-hi, fma} into {cvt_pkrtz, fdot2}:
// 4 VALU/level. Pass 2 deleted (mu pre-pass + pv fused into pass 1 via
// v_rcp) -> FETCH back to ~45MB. p stays f32 in the 32KB LDS slot.
// Envelope: 256 thr, 80KB LDS, lb(256,2) -- the proven 88-VGPR grant.
__global__ __launch_bounds__(256, 2) void scm_kernel(
    const float* __restrict__ u0, const float* __restrict__ v0,
    const float* __restrict__ t0, const float* __restrict__ s0,
    const float* __restrict__ hz, const float* __restrict__ akv,
    const float* __restrict__ akt, const float* __restrict__ tfo,
    const float* __restrict__ sfo, const float* __restrict__ uss,
    const float* __restrict__ vss, const float* __restrict__ usb,
    const float* __restrict__ vsb, const float* __restrict__ fcor,
    float* __restrict__ out)
{
    __shared__ uint4  Wsh[16 * 128];   // [k4][pair] 4 levels (hg*a,-e) = 32KB
    __shared__ uint4  CP4sh[8 * 128];  // [k8][pair] 8 levels -cp       = 16KB
    __shared__ float4 Psh[16 * 128];   // [k4][tsidx] particular soln   = 32KB

    const int ltid  = threadIdx.x;
    const int tid   = blockIdx.x * 256 + ltid;
    const int field = tid & 3;          // 0=u 1=v 2=t 3=s
    const int col   = tid >> 2;
    const int p     = ltid >> 1;        // pair: (u,v) share akv, (t,s) share akt
    const bool isTS = (field >= 2);
    const int tsidx = ((ltid >> 2) << 1) | (ltid & 1);  // 0..127 for ts lanes

    const float* ak  = isTS ? akt : akv;
    const float* st0 = (field == 0) ? u0 : (field == 1) ? v0 : (field == 2) ? t0 : s0;

    // Coriolis: alpha folded into W at build; rcor = beta/alpha per thread.
    float walpha = 1.0f, rcor = 0.0f;
    {
        float fc   = fcor[col];
        float dtfc = DTF * fc;
        float cff  = dtfc * dtfc;
        float cff1 = 1.0f / (1.0f + GAMMAC * GAMMAC * cff);
        float coefc = 1.0f - GAMMAC * (1.0f - GAMMAC) * cff;
        if (field == 0)      { walpha = cff1 * coefc; rcor =  dtfc / coefc; }
        else if (field == 1) { walpha = cff1 * coefc; rcor = -dtfc / coefc; }
    }

    float bnd0 = 0.f, bnd63 = 0.f;
    if (field == 0)      { bnd0 = -DTF * usb[col]; bnd63 = DTF * uss[col]; }
    else if (field == 1) { bnd0 = -DTF * vsb[col]; bnd63 = DTF * vss[col]; }

    const float* hzc = hz + (size_t)col * NZ;
    const float* akc = ak + (size_t)col * (NZ + 1);
    // uv lanes: fr aliases hzc (L1-hot, value unused) -> no ghost HBM traffic
    const float* fr  = isTS ? (((field == 2) ? tfo : sfo) + (size_t)col * NZ)
                            : hzc;
    float* op = out + ((size_t)field * NCOLS + col) * NZ;

    // ---- pre-pass (ts): mu = sum(dt*f)/sum(hz); also warms fr/hz in L1 ----
    float mu = 0.0f;
    if (isTS) {
        float sf = 0.f, sh = 0.f;
        const float4* fp = (const float4*)fr;
        const float4* hp = (const float4*)hzc;
        #pragma unroll
        for (int k4 = 0; k4 < 16; ++k4) {
            float4 f = fp[k4], h = hp[k4];
            sf += f.x + f.y + f.z + f.w;
            sh += h.x + h.y + h.z + h.w;
        }
        mu = (DTF * sf) * RCP(sh);
    }

    // ---- pass 1: build coefficients (f16) + particular solution p (f32) ----
    // a[k]=-2dt*ak[k]/(hz[k-1]+hz[k]); c[k]=a[k+1]; b=hz-a-c; g=1/(b-a*cp_prev)
    // publish hg'=hz*g*alpha, e=a*g, cp=c*g. p: c_k(p[k+1]-p[k]) = Pf_k-mu*Ph_k
    // with rc = 1/c_k = (hz_k+hz_{k+1})/(-2dt*ak[k+1]) via v_rcp.
    float gb0 = 0.f, gb63 = 0.f;
    {
        float cpprev = 0.f, aik = 0.f, hk = hzc[0];
        float Pf = 0.f, Ph = 0.f, pv = 0.f;
        uint4 wacc = {}; uint4 c8 = {}; float4 pacp;
        #pragma unroll
        for (int k = 0; k < NZ; ++k) {
            float frv = fr[k];
            // stage p[k] (prefix value BEFORE this level's update)
            if ((k & 3) == 0)      pacp.x = pv;
            else if ((k & 3) == 1) pacp.y = pv;
            else if ((k & 3) == 2) pacp.z = pv;
            else {
                pacp.w = pv;
                if (isTS) Psh[(k >> 2) * 128 + tsidx] = pacp;
            }
            float hk1 = 0.f, aik1 = 0.f, rc = 0.f;
            if (k < NZ - 1) {
                hk1 = hzc[k + 1];
                float tnum = (-2.0f * DTF) * akc[k + 1];
                float ssum = hk + hk1;
                aik1 = tnum * RCP(ssum);
                rc   = ssum * RCP(tnum);
            }
            float bk = hk - aik - aik1;
            float g  = RCP(fmaf(-aik, cpprev, bk));
            float cpk = aik1 * g;
            if (k == 0)      gb0  = bnd0  * g;   // ts: bnd=0 -> 0
            if (k == NZ - 1) gb63 = bnd63 * g;
            unsigned int   wv = packh2(hk * g * walpha, -aik * g);
            unsigned short cv = f16bits(-cpk);
            switch (k & 7) {
                case 0: wacc.x = wv; c8.x = cv; break;
                case 1: wacc.y = wv; c8.x |= ((unsigned)cv << 16); break;
                case 2: wacc.z = wv; c8.y = cv; break;
                case 3: wacc.w = wv; c8.y |= ((unsigned)cv << 16);
                        if ((ltid & 1) == 0) Wsh[(k >> 2) * 128 + p] = wacc;
                        break;
                case 4: wacc.x = wv; c8.z = cv; break;
                case 5: wacc.y = wv; c8.z |= ((unsigned)cv << 16); break;
                case 6: wacc.z = wv; c8.w = cv; break;
                default:
                    wacc.w = wv; c8.w |= ((unsigned)cv << 16);
                    if ((ltid & 1) == 0) {
                        Wsh[(k >> 2) * 128 + p]   = wacc;
                        CP4sh[(k >> 3) * 128 + p] = c8;
                    }
                    break;
            }
            Pf += DTF * frv;
            Ph += hk;
            if (k < NZ - 1) pv = fmaf(fmaf(-mu, Ph, Pf), rc, pv);
            cpprev = cpk; aik = aik1; hk = hk1;
            if ((k & 15) == 15) SBAR();
        }
    }

    // ---- load state, subtract p (exactly cancelled in the epilogue) ----
    float tau[NZ];
    {
        const float4* sp = (const float4*)(st0 + (size_t)col * NZ);
        #pragma unroll
        for (int k4 = 0; k4 < NZ / 4; ++k4) {
            float4 s = sp[k4];
            float4 pq = make_float4(0.f, 0.f, 0.f, 0.f);
            if (isTS) pq = Psh[k4 * 128 + tsidx];
            tau[4*k4+0] = s.x - pq.x; tau[4*k4+1] = s.y - pq.y;
            tau[4*k4+2] = s.z - pq.z; tau[4*k4+3] = s.w - pq.w;
        }
    }

    // deviation shift for t,s (homogeneous step conserves constants):
    // evolve s - mean(s); re-add at the end.
    float meanadd = 0.0f;
    if (isTS) {
        float ssum = 0.f;
        #pragma unroll
        for (int k = 0; k < NZ; ++k) ssum += tau[k];
        meanadd = ssum * (1.0f / NZ);
        #pragma unroll
        for (int k = 0; k < NZ; ++k) tau[k] -= meanadd;
    }

    __syncthreads();   // W/CP published; LDS read-only from here on
                       // (P slots are same-thread write->read, no hazard)

    // ---- 40 time steps: HOMOGENEOUS (uv: boundary regs at k=0/63) ----
    for (int n = 0; n < NT; ++n) {
        float dpprev = 0.f;
        #pragma unroll
        for (int q = 0; q < 16; ++q) {
            uint4 w = Wsh[q * 128 + p];
            #pragma unroll
            for (int i = 0; i < 4; ++i) {
                const int k = 4*q + i;
                unsigned wv = (i == 0) ? w.x : (i == 1) ? w.y
                            : (i == 2) ? w.z : w.w;
                float addend = (k == 0) ? gb0 : (k == NZ - 1) ? gb63 : 0.0f;
                float own = tau[k];
                float oth = dpp_swap1(own);             // u<->v partner
                float m   = fmaf(rcor, oth, own);       // ts: rcor=0 -> own
#if HAS_DOT2
                h2v bb = __builtin_amdgcn_cvt_pkrtz(m, dpprev);
                float dp = __builtin_amdgcn_fdot2(u2h(wv), bb, addend, false);
#else
                float t1 = fmaf(lo16f(wv), m, addend);  // hg'*m (+bnd)
                float dp = fmaf(hi16f(wv), dpprev, t1); // - e*dp_prev
#endif
                tau[k] = dp;
                dpprev = dp;
            }
            if ((q & 3) == 3) SBAR();
        }
        float xn = 0.f;
        uint4 c8;
        #pragma unroll
        for (int q = 15; q >= 0; --q) {
            if ((q & 1) == 1) c8 = CP4sh[(q >> 1) * 128 + p];
            #pragma unroll
            for (int i = 3; i >= 0; --i) {
                const int sel = ((q & 1) << 1) | (i >> 1);
                unsigned cw = (sel == 0) ? c8.x : (sel == 1) ? c8.y
                            : (sel == 2) ? c8.z : c8.w;
                float cv = (i & 1) ? hi16f(cw) : lo16f(cw);
                float x = fmaf(cv, xn, tau[4*q + i]);   // dp - cp*x_next
                tau[4*q + i] = x;
                xn = x;
            }
            if ((q & 3) == 0) SBAR();
        }
    }

    // ---- epilogue: out = tau_N + mean + NT*mu + p (p from LDS, exact) ----
    const float base = meanadd + (float)NT * mu;
    #pragma unroll
    for (int k4 = 0; k4 < NZ / 4; ++k4) {
        float4 pq = make_float4(0.f, 0.f, 0.f, 0.f);
        if (isTS) pq = Psh[k4 * 128 + tsidx];
        float4 w;
        w.x = tau[4*k4+0] + base + pq.x;
        w.y = tau[4*k4+1] + base + pq.y;
        w.z = tau[4*k4+2] + base + pq.z;
        w.w = tau[4*k4+3] + base + pq.w;
        ((float4*)op)[k4] = w;
    }
}

extern "C" void kernel_launch(void* const* d_in, const int* in_sizes, int n_in,
                              void* d_out, int out_size, void* d_ws, size_t ws_size,
                              hipStream_t stream) {
    const float* u0   = (const float*)d_in[0];
    const float* v0   = (const float*)d_in[1];
    const float* t0   = (const float*)d_in[2];
    const float* s0   = (const float*)d_in[3];
    const float* hz   = (const float*)d_in[4];
    const float* akv  = (const float*)d_in[5];
    const float* akt  = (const float*)d_in[6];
    const float* tfo  = (const float*)d_in[7];
    const float* sfo  = (const float*)d_in[8];
    const float* uss  = (const float*)d_in[9];
    const float* vss  = (const float*)d_in[10];
    const float* usb  = (const float*)d_in[11];
    const float* vsb  = (const float*)d_in[12];
    const float* fcor = (const float*)d_in[13];

    scm_kernel<<<dim3((NCOLS * 4) / 256), dim3(256), 0, stream>>>(
        u0, v0, t0, s0, hz, akv, akt, tfo, sfo, uss, vss, usb, vsb, fcor,
        (float*)d_out);
}

// Round 18
// 92.673 us; speedup vs baseline: 1.0795x; 1.0795x over previous
//
#include <hip/hip_runtime.h>
#include <hip/hip_bf16.h>

#define NCOLS 32768
#define NZ 64
#define NT 40
#define DTF 30.0f
#define GAMMAC 0.55f

typedef _Float16 f16;

// Cap the pre-RA scheduler's prefetch window (r4->r5 lesson).
#define SBAR() __builtin_amdgcn_sched_barrier(0)
#define RCP(x) __builtin_amdgcn_rcpf(x)

// swap lanes (0,1) and (2,3) within each quad: u<->v, t<->s
__device__ __forceinline__ float dpp_swap1(float x) {
    return __int_as_float(__builtin_amdgcn_mov_dpp(__float_as_int(x), 0xB1, 0xF, 0xF, true));
}
__device__ __forceinline__ unsigned int packh2(float a, float b) {
    union { f16 h[2]; unsigned int u; } v;
    v.h[0] = (f16)a; v.h[1] = (f16)b; return v.u;
}
__device__ __forceinline__ unsigned short f16bits(float a) {
    union { f16 h; unsigned short u; } v; v.h = (f16)a; return v.u;
}
__device__ __forceinline__ float lo16f(unsigned int x) {
    union { unsigned int u; f16 h[2]; } v; v.u = x; return (float)v.h[0];
}
__device__ __forceinline__ float hi16f(unsigned int x) {
    union { unsigned int u; f16 h[2]; } v; v.u = x; return (float)v.h[1];
}

// r18 = r17 minus dot2 (r17 lesson: cvt_pkrtz joined the dpprev serial
// chain, doubling dependent ops/level -> slower despite fewer ops; keep
// ONE fma on the chain, all unpacks off-chain). Retained from r17:
//  - affine decomposition (PROVEN absmax 0.25): ts evolves homogeneously,
//    p (particular soln) f32 in LDS, mu pre-pass, no FG in hot loop
//    -> 24 b128 LDS reads/step (16 W + 8 CP) vs r13's 32.
//  - v_rcp build (coefficients f16-rounded anyway), pv fused into pass 1.
// Envelope: 256 thr, 80KB LDS, lb(256,2) -- the proven 88-VGPR grant.
__global__ __launch_bounds__(256, 2) void scm_kernel(
    const float* __restrict__ u0, const float* __restrict__ v0,
    const float* __restrict__ t0, const float* __restrict__ s0,
    const float* __restrict__ hz, const float* __restrict__ akv,
    const float* __restrict__ akt, const float* __restrict__ tfo,
    const float* __restrict__ sfo, const float* __restrict__ uss,
    const float* __restrict__ vss, const float* __restrict__ usb,
    const float* __restrict__ vsb, const float* __restrict__ fcor,
    float* __restrict__ out)
{
    __shared__ uint4  Wsh[16 * 128];   // [k4][pair] 4 levels (hg*a,-e) = 32KB
    __shared__ uint4  CP4sh[8 * 128];  // [k8][pair] 8 levels -cp       = 16KB
    __shared__ float4 Psh[16 * 128];   // [k4][tsidx] particular soln   = 32KB

    const int ltid  = threadIdx.x;
    const int tid   = blockIdx.x * 256 + ltid;
    const int field = tid & 3;          // 0=u 1=v 2=t 3=s
    const int col   = tid >> 2;
    const int p     = ltid >> 1;        // pair: (u,v) share akv, (t,s) share akt
    const bool isTS = (field >= 2);
    const int tsidx = ((ltid >> 2) << 1) | (ltid & 1);  // 0..127 for ts lanes

    const float* ak  = isTS ? akt : akv;
    const float* st0 = (field == 0) ? u0 : (field == 1) ? v0 : (field == 2) ? t0 : s0;

    // Coriolis: alpha folded into W at build; rcor = beta/alpha per thread.
    float walpha = 1.0f, rcor = 0.0f;
    {
        float fc   = fcor[col];
        float dtfc = DTF * fc;
        float cff  = dtfc * dtfc;
        float cff1 = 1.0f / (1.0f + GAMMAC * GAMMAC * cff);
        float coefc = 1.0f - GAMMAC * (1.0f - GAMMAC) * cff;
        if (field == 0)      { walpha = cff1 * coefc; rcor =  dtfc / coefc; }
        else if (field == 1) { walpha = cff1 * coefc; rcor = -dtfc / coefc; }
    }

    float bnd0 = 0.f, bnd63 = 0.f;
    if (field == 0)      { bnd0 = -DTF * usb[col]; bnd63 = DTF * uss[col]; }
    else if (field == 1) { bnd0 = -DTF * vsb[col]; bnd63 = DTF * vss[col]; }

    const float* hzc = hz + (size_t)col * NZ;
    const float* akc = ak + (size_t)col * (NZ + 1);
    // uv lanes: fr aliases hzc (L1-hot, value unused) -> no ghost HBM traffic
    const float* fr  = isTS ? (((field == 2) ? tfo : sfo) + (size_t)col * NZ)
                            : hzc;
    float* op = out + ((size_t)field * NCOLS + col) * NZ;

    // ---- pre-pass (ts): mu = sum(dt*f)/sum(hz); also warms fr/hz in L1 ----
    float mu = 0.0f;
    if (isTS) {
        float sf = 0.f, sh = 0.f;
        const float4* fp = (const float4*)fr;
        const float4* hp = (const float4*)hzc;
        #pragma unroll
        for (int k4 = 0; k4 < 16; ++k4) {
            float4 f = fp[k4], h = hp[k4];
            sf += f.x + f.y + f.z + f.w;
            sh += h.x + h.y + h.z + h.w;
        }
        mu = (DTF * sf) * RCP(sh);
    }

    // ---- pass 1: build coefficients (f16) + particular solution p (f32) ----
    // a[k]=-2dt*ak[k]/(hz[k-1]+hz[k]); c[k]=a[k+1]; b=hz-a-c; g=1/(b-a*cp_prev)
    // publish hg'=hz*g*alpha, e=a*g, cp=c*g. p: c_k(p[k+1]-p[k]) = Pf_k-mu*Ph_k
    // with rc = 1/c_k = (hz_k+hz_{k+1})/(-2dt*ak[k+1]) via v_rcp.
    float gb0 = 0.f, gb63 = 0.f;
    {
        float cpprev = 0.f, aik = 0.f, hk = hzc[0];
        float Pf = 0.f, Ph = 0.f, pv = 0.f;
        uint4 wacc = {}; uint4 c8 = {}; float4 pacp;
        #pragma unroll
        for (int k = 0; k < NZ; ++k) {
            float frv = fr[k];
            // stage p[k] (prefix value BEFORE this level's update)
            if ((k & 3) == 0)      pacp.x = pv;
            else if ((k & 3) == 1) pacp.y = pv;
            else if ((k & 3) == 2) pacp.z = pv;
            else {
                pacp.w = pv;
                if (isTS) Psh[(k >> 2) * 128 + tsidx] = pacp;
            }
            float hk1 = 0.f, aik1 = 0.f, rc = 0.f;
            if (k < NZ - 1) {
                hk1 = hzc[k + 1];
                float tnum = (-2.0f * DTF) * akc[k + 1];
                float ssum = hk + hk1;
                aik1 = tnum * RCP(ssum);
                rc   = ssum * RCP(tnum);
            }
            float bk = hk - aik - aik1;
            float g  = RCP(fmaf(-aik, cpprev, bk));
            float cpk = aik1 * g;
            if (k == 0)      gb0  = bnd0  * g;   // ts: bnd=0 -> 0
            if (k == NZ - 1) gb63 = bnd63 * g;
            unsigned int   wv = packh2(hk * g * walpha, -aik * g);
            unsigned short cv = f16bits(-cpk);
            switch (k & 7) {
                case 0: wacc.x = wv; c8.x = cv; break;
                case 1: wacc.y = wv; c8.x |= ((unsigned)cv << 16); break;
                case 2: wacc.z = wv; c8.y = cv; break;
                case 3: wacc.w = wv; c8.y |= ((unsigned)cv << 16);
                        if ((ltid & 1) == 0) Wsh[(k >> 2) * 128 + p] = wacc;
                        break;
                case 4: wacc.x = wv; c8.z = cv; break;
                case 5: wacc.y = wv; c8.z |= ((unsigned)cv << 16); break;
                case 6: wacc.z = wv; c8.w = cv; break;
                default:
                    wacc.w = wv; c8.w |= ((unsigned)cv << 16);
                    if ((ltid & 1) == 0) {
                        Wsh[(k >> 2) * 128 + p]   = wacc;
                        CP4sh[(k >> 3) * 128 + p] = c8;
                    }
                    break;
            }
            Pf += DTF * frv;
            Ph += hk;
            if (k < NZ - 1) pv = fmaf(fmaf(-mu, Ph, Pf), rc, pv);
            cpprev = cpk; aik = aik1; hk = hk1;
            if ((k & 15) == 15) SBAR();
        }
    }

    // ---- load state, subtract p (exactly cancelled in the epilogue) ----
    float tau[NZ];
    {
        const float4* sp = (const float4*)(st0 + (size_t)col * NZ);
        #pragma unroll
        for (int k4 = 0; k4 < NZ / 4; ++k4) {
            float4 s = sp[k4];
            float4 pq = make_float4(0.f, 0.f, 0.f, 0.f);
            if (isTS) pq = Psh[k4 * 128 + tsidx];
            tau[4*k4+0] = s.x - pq.x; tau[4*k4+1] = s.y - pq.y;
            tau[4*k4+2] = s.z - pq.z; tau[4*k4+3] = s.w - pq.w;
        }
    }

    // deviation shift for t,s (homogeneous step conserves constants):
    // evolve s - mean(s); re-add at the end.
    float meanadd = 0.0f;
    if (isTS) {
        float ssum = 0.f;
        #pragma unroll
        for (int k = 0; k < NZ; ++k) ssum += tau[k];
        meanadd = ssum * (1.0f / NZ);
        #pragma unroll
        for (int k = 0; k < NZ; ++k) tau[k] -= meanadd;
    }

    __syncthreads();   // W/CP published; LDS read-only from here on
                       // (P slots are same-thread write->read, no hazard)

    // ---- 40 time steps: HOMOGENEOUS (uv: boundary regs at k=0/63) ----
    for (int n = 0; n < NT; ++n) {
        float dpprev = 0.f;
        #pragma unroll
        for (int q = 0; q < 16; ++q) {
            uint4 w = Wsh[q * 128 + p];
            #pragma unroll
            for (int i = 0; i < 4; ++i) {
                const int k = 4*q + i;
                unsigned wv = (i == 0) ? w.x : (i == 1) ? w.y
                            : (i == 2) ? w.z : w.w;
                float addend = (k == 0) ? gb0 : (k == NZ - 1) ? gb63 : 0.0f;
                float own = tau[k];
                float oth = dpp_swap1(own);             // u<->v partner
                float m   = fmaf(rcor, oth, own);       // ts: rcor=0 -> own
                float t1  = fmaf(lo16f(wv), m, addend); // hg'*m (+bnd), off-chain
                float dp  = fmaf(hi16f(wv), dpprev, t1);// chain: ONE fma
                tau[k] = dp;
                dpprev = dp;
            }
            if ((q & 3) == 3) SBAR();
        }
        float xn = 0.f;
        uint4 c8;
        #pragma unroll
        for (int q = 15; q >= 0; --q) {
            if ((q & 1) == 1) c8 = CP4sh[(q >> 1) * 128 + p];
            #pragma unroll
            for (int i = 3; i >= 0; --i) {
                const int sel = ((q & 1) << 1) | (i >> 1);
                unsigned cw = (sel == 0) ? c8.x : (sel == 1) ? c8.y
                            : (sel == 2) ? c8.z : c8.w;
                float cv = (i & 1) ? hi16f(cw) : lo16f(cw);
                float x = fmaf(cv, xn, tau[4*q + i]);   // chain: ONE fma
                tau[4*q + i] = x;
                xn = x;
            }
            if ((q & 3) == 0) SBAR();
        }
    }

    // ---- epilogue: out = tau_N + mean + NT*mu + p (p from LDS, exact) ----
    const float base = meanadd + (float)NT * mu;
    #pragma unroll
    for (int k4 = 0; k4 < NZ / 4; ++k4) {
        float4 pq = make_float4(0.f, 0.f, 0.f, 0.f);
        if (isTS) pq = Psh[k4 * 128 + tsidx];
        float4 w;
        w.x = tau[4*k4+0] + base + pq.x;
        w.y = tau[4*k4+1] + base + pq.y;
        w.z = tau[4*k4+2] + base + pq.z;
        w.w = tau[4*k4+3] + base + pq.w;
        ((float4*)op)[k4] = w;
    }
}

extern "C" void kernel_launch(void* const* d_in, const int* in_sizes, int n_in,
                              void* d_out, int out_size, void* d_ws, size_t ws_size,
                              hipStream_t stream) {
    const float* u0   = (const float*)d_in[0];
    const float* v0   = (const float*)d_in[1];
    const float* t0   = (const float*)d_in[2];
    const float* s0   = (const float*)d_in[3];
    const float* hz   = (const float*)d_in[4];
    const float* akv  = (const float*)d_in[5];
    const float* akt  = (const float*)d_in[6];
    const float* tfo  = (const float*)d_in[7];
    const float* sfo  = (const float*)d_in[8];
    const float* uss  = (const float*)d_in[9];
    const float* vss  = (const float*)d_in[10];
    const float* usb  = (const float*)d_in[11];
    const float* vsb  = (const float*)d_in[12];
    const float* fcor = (const float*)d_in[13];

    scm_kernel<<<dim3((NCOLS * 4) / 256), dim3(256), 0, stream>>>(
        u0, v0, t0, s0, hz, akv, akt, tfo, sfo, uss, vss, usb, vsb, fcor,
        (float*)d_out);
}